// Round 1
// baseline (2903.874 us; speedup 1.0000x reference)
//
#include <hip/hip_runtime.h>
#include <cstdint>

#define N_A 40000
#define N_P 100000
#define N_T 20000
#define D 128
#define OUT_DIM 64
#define E_AP 500000
#define E_PT 800000

static inline int ceil_div(int a, int b){ return (a + b - 1) / b; }

// ---------------- CSR build ----------------
__global__ void hist_kernel(const int* __restrict__ dst, int E, int* __restrict__ cnt){
  int i = blockIdx.x * blockDim.x + threadIdx.x;
  if (i < E) atomicAdd(&cnt[dst[i]], 1);
}

__global__ void block_sums_kernel(const int* __restrict__ cnt, int n, int* __restrict__ bsums){
  __shared__ int red[256];
  int b = blockIdx.x, t = threadIdx.x;
  int base = b * 1024;
  int s = 0;
  for (int i = t; i < 1024; i += 256){ int idx = base + i; if (idx < n) s += cnt[idx]; }
  red[t] = s; __syncthreads();
  for (int off = 128; off > 0; off >>= 1){ if (t < off) red[t] += red[t + off]; __syncthreads(); }
  if (t == 0) bsums[b] = red[0];
}

__global__ void scan_bsums_kernel(int* bsums, int nb){
  __shared__ int sh[128];
  int t = threadIdx.x;
  int v = (t < nb) ? bsums[t] : 0;
  sh[t] = v; __syncthreads();
  int inc = v;
  for (int off = 1; off < 128; off <<= 1){
    int x = (t >= off) ? sh[t - off] : 0; __syncthreads();
    inc += x; sh[t] = inc; __syncthreads();
  }
  if (t < nb) bsums[t] = inc - v;   // exclusive
}

__global__ void scan_final_kernel(const int* __restrict__ cnt, int n, const int* __restrict__ bsums,
                                  int* __restrict__ rowptr, int E){
  __shared__ int sh[256];
  int b = blockIdx.x, t = threadIdx.x;
  int base = b * 1024 + t * 4;
  int v[4]; int s = 0;
  #pragma unroll
  for (int j = 0; j < 4; j++){ int idx = base + j; v[j] = (idx < n) ? cnt[idx] : 0; s += v[j]; }
  sh[t] = s; __syncthreads();
  int inc = s;
  for (int off = 1; off < 256; off <<= 1){
    int x = (t >= off) ? sh[t - off] : 0; __syncthreads();
    inc += x; sh[t] = inc; __syncthreads();
  }
  int run = inc - s + bsums[b];
  #pragma unroll
  for (int j = 0; j < 4; j++){ int idx = base + j; if (idx < n) rowptr[idx] = run; run += v[j]; }
  if (b == 0 && t == 0) rowptr[n] = E;
}

__global__ void cursor_inv_kernel(const int* __restrict__ rowptr, const int* __restrict__ cnt,
                                  int n, int* __restrict__ cursor, float* __restrict__ inv){
  int i = blockIdx.x * blockDim.x + threadIdx.x;
  if (i < n){
    cursor[i] = rowptr[i];
    int c = cnt[i];
    inv[i] = 1.0f / (float)(c > 0 ? c : 1);
  }
}

__global__ void fill_kernel(const int* __restrict__ src, const int* __restrict__ dst, int E,
                            int* __restrict__ cursor, int* __restrict__ eidx){
  int i = blockIdx.x * blockDim.x + threadIdx.x;
  if (i < E){
    int d = dst[i];
    int pos = atomicAdd(&cursor[d], 1);
    eidx[pos] = src[i];
  }
}

// ---------------- weight/bias combine for the paper relation pair ----------------
// wrc[s][l] = W_r[s,l,0] + W_r[s,l,3] ; bc[s][l] = b_l[s,l,0] + b_l[s,l,3]
__global__ void combine_wr_kernel(const float* __restrict__ Wr, float* __restrict__ wrc){
  int i = blockIdx.x * blockDim.x + threadIdx.x;
  if (i < 6 * D * D){
    int sl = i >> 14; int off = i & (D * D - 1);
    wrc[i] = Wr[(size_t)(sl * 4 + 0) * D * D + off] + Wr[(size_t)(sl * 4 + 3) * D * D + off];
  }
}

__global__ void combine_bias_kernel(const float* __restrict__ bl, float* __restrict__ bcomb){
  int i = blockIdx.x * blockDim.x + threadIdx.x;
  if (i < 6 * D){
    int sl = i >> 7; int off = i & (D - 1);
    bcomb[i] = bl[(size_t)(sl * 4 + 0) * D + off] + bl[(size_t)(sl * 4 + 3) * D + off];
  }
}

// ---------------- mean aggregation (CSR, one wave per dst row) ----------------
__global__ __launch_bounds__(256)
void agg_mean_kernel(const int* __restrict__ rowptr, const int* __restrict__ eidx,
                     const float* __restrict__ inv, const float* __restrict__ xsrc,
                     float* __restrict__ out, int ndst){
  int w = (blockIdx.x * blockDim.x + threadIdx.x) >> 6;
  int lane = threadIdx.x & 63;
  if (w >= ndst) return;
  int beg = rowptr[w], end = rowptr[w + 1];
  float2 a0 = make_float2(0.f, 0.f), a1 = make_float2(0.f, 0.f);
  int e = beg;
  for (; e + 2 <= end; e += 2){
    int s0 = eidx[e], s1 = eidx[e + 1];
    float2 v0 = ((const float2*)(xsrc + (size_t)s0 * D))[lane];
    float2 v1 = ((const float2*)(xsrc + (size_t)s1 * D))[lane];
    a0.x += v0.x; a0.y += v0.y; a1.x += v1.x; a1.y += v1.y;
  }
  if (e < end){
    int s0 = eidx[e];
    float2 v0 = ((const float2*)(xsrc + (size_t)s0 * D))[lane];
    a0.x += v0.x; a0.y += v0.y;
  }
  float iv = inv[w];
  float2 r = make_float2((a0.x + a1.x) * iv, (a0.y + a1.y) * iv);
  ((float2*)(out + (size_t)w * D))[lane] = r;
}

// ---------------- fused multi-input GEMM: out = relu(sum_i in_i @ W_i + bias) ----------------
// in_i: [nrows,128], W_i: [128,128] row-major, bias: [128]
// Block: 256 threads, tile 64 rows x 128 cols; per-thread 8 rows x 4 cols.
template<int NIN, bool RELU>
__global__ __launch_bounds__(256)
void gemm128_fused(const float* __restrict__ in0, const float* __restrict__ W0,
                   const float* __restrict__ in1, const float* __restrict__ W1,
                   const float* __restrict__ in2, const float* __restrict__ W2,
                   const float* __restrict__ bias, float* __restrict__ out, int nrows){
  __shared__ float sW[32 * 128];   // k-chunk of W, row-major [32][128]
  __shared__ float sIn[32 * 68];   // transposed input chunk [k][row], padded stride 68

  const int tid  = threadIdx.x;
  const int tcol = tid & 31;       // 32 col-groups of 4
  const int trow = tid >> 5;       // 8 row-groups of 8
  const int row0 = blockIdx.x * 64;

  float4 acc[8];
  #pragma unroll
  for (int r = 0; r < 8; ++r) acc[r] = make_float4(0.f, 0.f, 0.f, 0.f);

  const float* ins[3] = {in0, in1, in2};
  const float* Ws[3]  = {W0, W1, W2};

  #pragma unroll
  for (int inp = 0; inp < NIN; ++inp){
    const float* in = ins[inp];
    const float* W  = Ws[inp];
    for (int kc = 0; kc < 4; ++kc){
      // stage W rows [kc*32, kc*32+32) -- 4096 contiguous floats
      const float4* Wg = (const float4*)(W + (size_t)kc * 32 * 128);
      float4* sWf4 = (float4*)sW;
      #pragma unroll
      for (int i = 0; i < 4; ++i) sWf4[tid + i * 256] = Wg[tid + i * 256];
      // stage input chunk transposed
      #pragma unroll
      for (int j = 0; j < 2; ++j){
        int f = 2 * tid + j;
        int r = f >> 3;
        int kk = (f & 7) * 4;
        int gr = row0 + r; if (gr >= nrows) gr = nrows - 1;
        float4 v = *(const float4*)(in + (size_t)gr * 128 + kc * 32 + kk);
        sIn[(kk + 0) * 68 + r] = v.x;
        sIn[(kk + 1) * 68 + r] = v.y;
        sIn[(kk + 2) * 68 + r] = v.z;
        sIn[(kk + 3) * 68 + r] = v.w;
      }
      __syncthreads();
      #pragma unroll
      for (int k = 0; k < 32; ++k){
        float4 w = ((const float4*)(sW + k * 128))[tcol];
        #pragma unroll
        for (int r = 0; r < 8; ++r){
          float a = sIn[k * 68 + trow * 8 + r];
          acc[r].x += a * w.x; acc[r].y += a * w.y;
          acc[r].z += a * w.z; acc[r].w += a * w.w;
        }
      }
      __syncthreads();
    }
  }

  float4 b = ((const float4*)bias)[tcol];
  #pragma unroll
  for (int r = 0; r < 8; ++r){
    int gr = row0 + trow * 8 + r;
    if (gr < nrows){
      float4 v = make_float4(acc[r].x + b.x, acc[r].y + b.y, acc[r].z + b.z, acc[r].w + b.w);
      if (RELU){
        v.x = fmaxf(v.x, 0.f); v.y = fmaxf(v.y, 0.f);
        v.z = fmaxf(v.z, 0.f); v.w = fmaxf(v.w, 0.f);
      }
      ((float4*)(out + (size_t)gr * 128))[tcol] = v;
    }
  }
}

// ---------------- head: logits = (ma@Wm + bm) / (ta@Wt + bt) @ W2 + b2 ----------------
__global__ __launch_bounds__(256)
void head_kernel(const float* __restrict__ ma, const float* __restrict__ ta,
                 const float* __restrict__ Wm, const float* __restrict__ bm,
                 const float* __restrict__ Wt, const float* __restrict__ bt,
                 const float* __restrict__ W2, const float* __restrict__ b2,
                 float* __restrict__ out, int na){
  int w = (blockIdx.x * blockDim.x + threadIdx.x) >> 6;
  int l = threadIdx.x & 63;
  if (w >= na) return;
  const float* mrow = ma + (size_t)w * D;
  const float* trow = ta + (size_t)w * D;
  float accm = 0.f, acct = 0.f;
  #pragma unroll 4
  for (int k = 0; k < D; ++k){
    float av = mrow[k], tv = trow[k];
    accm += av * Wm[k * OUT_DIM + l];
    acct += tv * Wt[k * OUT_DIM + l];
  }
  float contrib = (acct + bt[l]) * W2[l];
  #pragma unroll
  for (int off = 32; off > 0; off >>= 1) contrib += __shfl_xor(contrib, off, 64);
  float temp = contrib + b2[0];
  out[(size_t)w * OUT_DIM + l] = (accm + bm[l]) / temp;
}

// ---------------- host ----------------
extern "C" void kernel_launch(void* const* d_in, const int* in_sizes, int n_in,
                              void* d_out, int out_size, void* d_ws, size_t ws_size,
                              hipStream_t stream){
  const float* x_author    = (const float*)d_in[0];
  const float* x_paper     = (const float*)d_in[1];
  const float* x_term      = (const float*)d_in[2];
  const float* W_l         = (const float*)d_in[3];
  const float* b_l         = (const float*)d_in[4];
  const float* W_r         = (const float*)d_in[5];
  const float* lin_model_W = (const float*)d_in[6];
  const float* lin_model_b = (const float*)d_in[7];
  const float* lin_temp_W  = (const float*)d_in[8];
  const float* lin_temp_b  = (const float*)d_in[9];
  const float* lin2_W      = (const float*)d_in[10];
  const float* lin2_b      = (const float*)d_in[11];
  const int* src_ap = (const int*)d_in[12];
  const int* dst_ap = (const int*)d_in[13];
  const int* src_pa = (const int*)d_in[14];
  const int* dst_pa = (const int*)d_in[15];
  const int* src_pt = (const int*)d_in[16];
  const int* dst_pt = (const int*)d_in[17];
  const int* src_tp = (const int*)d_in[18];
  const int* dst_tp = (const int*)d_in[19];

  // ---- workspace carve (total ~335 MB) ----
  char* wp = (char*)d_ws;
  auto alloc = [&](size_t bytes)->void*{
    void* r = (void*)wp; wp += (bytes + 255) & ~(size_t)255; return r;
  };
  // CSR: a->p (dst papers)
  int*   rowptr_ap = (int*)alloc((N_P + 1) * 4);
  int*   cnt_ap    = (int*)alloc(N_P * 4);
  int*   cur_ap    = (int*)alloc(N_P * 4);
  int*   eidx_ap   = (int*)alloc((size_t)E_AP * 4);
  float* inv_ap    = (float*)alloc(N_P * 4);
  // p->a (dst authors)
  int*   rowptr_pa = (int*)alloc((N_A + 1) * 4);
  int*   cnt_pa    = (int*)alloc(N_A * 4);
  int*   cur_pa    = (int*)alloc(N_A * 4);
  int*   eidx_pa   = (int*)alloc((size_t)E_AP * 4);
  float* inv_pa    = (float*)alloc(N_A * 4);
  // p->t (dst terms)
  int*   rowptr_pt = (int*)alloc((N_T + 1) * 4);
  int*   cnt_pt    = (int*)alloc(N_T * 4);
  int*   cur_pt    = (int*)alloc(N_T * 4);
  int*   eidx_pt   = (int*)alloc((size_t)E_PT * 4);
  float* inv_pt    = (float*)alloc(N_T * 4);
  // t->p (dst papers)
  int*   rowptr_tp = (int*)alloc((N_P + 1) * 4);
  int*   cnt_tp    = (int*)alloc(N_P * 4);
  int*   cur_tp    = (int*)alloc(N_P * 4);
  int*   eidx_tp   = (int*)alloc((size_t)E_PT * 4);
  float* inv_tp    = (float*)alloc(N_P * 4);
  int*   bsums     = (int*)alloc(1024 * 4);
  // feature buffers
  float* A0    = (float*)alloc((size_t)N_A * D * 4);   // ma
  float* A1    = (float*)alloc((size_t)N_A * D * 4);
  float* TA    = (float*)alloc((size_t)N_A * D * 4);   // ta (temperature stack author out)
  float* aggA  = (float*)alloc((size_t)N_A * D * 4);
  float* P0    = (float*)alloc((size_t)N_P * D * 4);   // mp
  float* P1    = (float*)alloc((size_t)N_P * D * 4);
  float* aggP1 = (float*)alloc((size_t)N_P * D * 4);
  float* aggP2 = (float*)alloc((size_t)N_P * D * 4);
  float* T0    = (float*)alloc((size_t)N_T * D * 4);   // mt
  float* T1    = (float*)alloc((size_t)N_T * D * 4);
  float* aggT  = (float*)alloc((size_t)N_T * D * 4);
  float* wrc   = (float*)alloc((size_t)6 * D * D * 4);
  float* bcomb = (float*)alloc((size_t)6 * D * 4);

  // ---- build CSR for the 4 relations ----
  auto build = [&](const int* src, const int* dst, int E, int n,
                   int* rowptr, int* cnt, int* cursor, int* eidx, float* inv){
    hipMemsetAsync(cnt, 0, (size_t)n * 4, stream);
    hist_kernel<<<ceil_div(E, 256), 256, 0, stream>>>(dst, E, cnt);
    int nb = ceil_div(n, 1024);
    block_sums_kernel<<<nb, 256, 0, stream>>>(cnt, n, bsums);
    scan_bsums_kernel<<<1, 128, 0, stream>>>(bsums, nb);
    scan_final_kernel<<<nb, 256, 0, stream>>>(cnt, n, bsums, rowptr, E);
    cursor_inv_kernel<<<ceil_div(n, 256), 256, 0, stream>>>(rowptr, cnt, n, cursor, inv);
    fill_kernel<<<ceil_div(E, 256), 256, 0, stream>>>(src, dst, E, cursor, eidx);
  };
  build(src_ap, dst_ap, E_AP, N_P, rowptr_ap, cnt_ap, cur_ap, eidx_ap, inv_ap);
  build(src_pa, dst_pa, E_AP, N_A, rowptr_pa, cnt_pa, cur_pa, eidx_pa, inv_pa);
  build(src_pt, dst_pt, E_PT, N_T, rowptr_pt, cnt_pt, cur_pt, eidx_pt, inv_pt);
  build(src_tp, dst_tp, E_PT, N_P, rowptr_tp, cnt_tp, cur_tp, eidx_tp, inv_tp);

  combine_wr_kernel<<<ceil_div(6 * D * D, 256), 256, 0, stream>>>(W_r, wrc);
  combine_bias_kernel<<<ceil_div(6 * D, 256), 256, 0, stream>>>(b_l, bcomb);

  auto Wl  = [&](int s, int l, int r){ return W_l + (size_t)((s * 2 + l) * 4 + r) * D * D; };
  auto Wrp = [&](int s, int l, int r){ return W_r + (size_t)((s * 2 + l) * 4 + r) * D * D; };
  auto Bl  = [&](int s, int l, int r){ return b_l + (size_t)((s * 2 + l) * 4 + r) * D; };
  auto WRC = [&](int s, int l){ return wrc + (size_t)(s * 2 + l) * D * D; };
  auto BC  = [&](int s, int l){ return bcomb + (size_t)(s * 2 + l) * D; };

  auto agg = [&](const int* rowptr, const int* eidx, const float* inv,
                 const float* xsrc, float* outp, int ndst){
    agg_mean_kernel<<<ceil_div(ndst, 4), 256, 0, stream>>>(rowptr, eidx, inv, xsrc, outp, ndst);
  };

  // one hetero layer; null output pointer -> skip that node type
  auto layer = [&](const float* ia, const float* ip, const float* it, int s, int l,
                   float* oa, float* op, float* ot){
    if (op){
      agg(rowptr_ap, eidx_ap, inv_ap, ia, aggP1, N_P);
      agg(rowptr_tp, eidx_tp, inv_tp, it, aggP2, N_P);
      gemm128_fused<3, true><<<ceil_div(N_P, 64), 256, 0, stream>>>(
          aggP1, Wl(s, l, 0), aggP2, Wl(s, l, 3), ip, WRC(s, l), BC(s, l), op, N_P);
    }
    if (oa){
      agg(rowptr_pa, eidx_pa, inv_pa, ip, aggA, N_A);
      gemm128_fused<2, true><<<ceil_div(N_A, 64), 256, 0, stream>>>(
          aggA, Wl(s, l, 1), ia, Wrp(s, l, 1), nullptr, nullptr, Bl(s, l, 1), oa, N_A);
    }
    if (ot){
      agg(rowptr_pt, eidx_pt, inv_pt, ip, aggT, N_T);
      gemm128_fused<2, true><<<ceil_div(N_T, 64), 256, 0, stream>>>(
          aggT, Wl(s, l, 2), it, Wrp(s, l, 2), nullptr, nullptr, Bl(s, l, 2), ot, N_T);
    }
  };

  float* out_logits = (float*)d_out;
  float* out_oa = out_logits + (size_t)N_A * OUT_DIM;
  float* out_op = out_oa + (size_t)N_A * D;
  float* out_ot = out_op + (size_t)N_P * D;

  // stack 0 (model) on raw features -> ma,mp,mt in A0,P0,T0
  layer(x_author, x_paper, x_term, 0, 0, A1, P1, T1);
  layer(A1, P1, T1, 0, 1, A0, P0, T0);
  // stack 1 (temperature) on ma,mp,mt; only author output of layer 1 needed
  layer(A0, P0, T0, 1, 0, A1, P1, T1);
  layer(A1, P1, T1, 1, 1, TA, nullptr, nullptr);
  // stack 2 (convs) on raw features -> directly into d_out
  layer(x_author, x_paper, x_term, 2, 0, A1, P1, T1);
  layer(A1, P1, T1, 2, 1, out_oa, out_op, out_ot);
  // head: logits / temperature
  head_kernel<<<ceil_div(N_A, 4), 256, 0, stream>>>(
      A0, TA, lin_model_W, lin_model_b, lin_temp_W, lin_temp_b,
      lin2_W, lin2_b, out_logits, N_A);
}